// Round 1
// baseline (310.094 us; speedup 1.0000x reference)
//
#include <hip/hip_runtime.h>
#include <hip/hip_bf16.h>
#include <cstdint>
#include <cstddef>

// ---------------------------------------------------------------------------
// GatingNetwork: weights = top2-softmax( W2^T . gelu( LN( x.W1 + b1 ) ) + b2 )
//                lb_loss = 0.01 * 8 * sum_e f_e * P_e
// Strategy: fp16x2 (Markidis) 3-product MFMA GEMM for x@W1 (fp32-grade
// accuracy so top-2 selection matches the fp32 reference), fully fused
// LN/GELU/logits/top-2 epilogue. Scales: A=64x, B=64w, lo-of-B pre-scaled by
// 2^8 to dodge fp16 denormal flush; all products land at scale 2^12.
// ---------------------------------------------------------------------------

typedef _Float16 f16;
typedef _Float16 f16x8 __attribute__((ext_vector_type(8)));
typedef float f32x4 __attribute__((ext_vector_type(4)));

#define B_ROWS 65536
#define D_DIM 1024
#define H_DIM 512
#define E_DIM 8
#define BM 128
#define BK 32
#define NCHUNK (D_DIM / BK)            // 32
#define LDP 40                          // padded LDS row stride in f16 (80B: 2-way banks = free)
#define THREADS 512

#define IMG_ELEMS (H_DIM * LDP)         // 20480 f16 per K-chunk image
#define IMG_TOTAL (NCHUNK * IMG_ELEMS)  // 655360 f16 = 1,310,720 B per matrix
#define ACC_OFF_BYTES ((size_t)2 * IMG_TOTAL * sizeof(f16))  // 2,621,440

// ---------------- prep: split W1 into fp16 hi/lo padded chunk images --------
__global__ void prep_split(const float* __restrict__ W1,
                           f16* __restrict__ wh, f16* __restrict__ wl) {
  int g = blockIdx.x * 256 + threadIdx.x;     // 0 .. 1024*512-1, flat [k][h]
  int k = g >> 9;
  int h = g & (H_DIM - 1);
  float v = W1[g] * 64.0f;                    // scale 64
  f16 hi = (f16)v;
  f16 lo = (f16)((v - (float)hi) * 256.0f);   // residual pre-scaled 2^8 (stays normal)
  int c = k >> 5, kk = k & 31;
  int idx = c * IMG_ELEMS + h * LDP + kk;
  wh[idx] = hi;
  wl[idx] = lo;
}

__global__ void zero_acc(float* __restrict__ acc) {
  if (threadIdx.x < 16) acc[threadIdx.x] = 0.0f;
}

// ---------------- main fused kernel ----------------------------------------
__global__ __launch_bounds__(THREADS, 2) void fused_main(
    const float* __restrict__ x,
    const f16* __restrict__ whImg, const f16* __restrict__ wlImg,
    const float* __restrict__ b1, const float* __restrict__ lnw,
    const float* __restrict__ lnb, const float* __restrict__ W2,
    const float* __restrict__ b2, float* __restrict__ out,
    float* __restrict__ gacc) {
  __shared__ f16 sWh[H_DIM * LDP];      // 40960 B
  __shared__ f16 sWl[H_DIM * LDP];      // 40960 B
  __shared__ f16 sXh[BM * LDP];         // 10240 B
  __shared__ f16 sXl[BM * LDP];         // 10240 B
  __shared__ float sW2T[E_DIM][H_DIM];  // 16384 B (transposed: conflict-free reads)
  __shared__ float sB1[H_DIM];          // pre-scaled x4096
  __shared__ float sLnw[H_DIM];
  __shared__ float sLnb[H_DIM];
  __shared__ float sStat[4][BM][2];     // per-N-wave partial (deterministic reduce)
  __shared__ float sLog[4][BM][E_DIM];  // per-N-wave partial logits
  __shared__ float sMu[BM];
  __shared__ float sRs[BM];
  __shared__ float sF[E_DIM];
  __shared__ float sP[E_DIM];

  const int tid = threadIdx.x;
  const int lane = tid & 63;
  const int wv = tid >> 6;        // 0..7
  const int wm = wv >> 2;         // 0..1  (64-row half)
  const int wn = wv & 3;          // 0..3  (128-col slice)
  const int l15 = lane & 15;
  const int l4 = lane >> 4;       // 0..3
  const int64_t row0 = (int64_t)blockIdx.x * BM;

  // prolog staging of small per-column params
  {
    int i = tid;                  // THREADS == H_DIM
    sB1[i] = b1[i] * 4096.0f;     // h is held at scale 2^12
    sLnw[i] = lnw[i];
    sLnb[i] = lnb[i];
  }
  for (int i = tid; i < H_DIM * E_DIM; i += THREADS) {
    int cc = i >> 3, e = i & 7;
    sW2T[e][cc] = W2[i];
  }
  if (tid < E_DIM) { sF[tid] = 0.0f; sP[tid] = 0.0f; }

  f32x4 acc[4][8];
#pragma unroll
  for (int m = 0; m < 4; ++m)
#pragma unroll
    for (int n = 0; n < 8; ++n) acc[m][n] = (f32x4){0.f, 0.f, 0.f, 0.f};

  const int xr = tid >> 2;         // 0..127
  const int xs4 = (tid & 3) * 8;   // 0,8,16,24

  for (int c = 0; c < NCHUNK; ++c) {
    __syncthreads();  // previous chunk's reads complete before overwrite
    // ---- stage W chunk (reg path; 80B/thread/image) ----
    {
      const f16* __restrict__ srcH = whImg + (size_t)c * IMG_ELEMS;
      const f16* __restrict__ srcL = wlImg + (size_t)c * IMG_ELEMS;
#pragma unroll
      for (int i = 0; i < 5; ++i) {
        int off = (i * THREADS + tid) * 8;
        *(f16x8*)&sWh[off] = *(const f16x8*)&srcH[off];
        *(f16x8*)&sWl[off] = *(const f16x8*)&srcL[off];
      }
    }
    // ---- stage x chunk, split fp32 -> (hi, lo) fp16 at scale 64 ----
    {
      const float* xp = x + (row0 + xr) * D_DIM + c * BK + xs4;
      float4 v0 = *(const float4*)xp;
      float4 v1 = *(const float4*)(xp + 4);
      float vv[8] = {v0.x, v0.y, v0.z, v0.w, v1.x, v1.y, v1.z, v1.w};
      f16x8 hi, lo;
#pragma unroll
      for (int j = 0; j < 8; ++j) {
        float v = vv[j] * 64.0f;
        f16 h = (f16)v;
        hi[j] = h;
        lo[j] = (f16)(v - (float)h);  // residual at scale 64 (normal range)
      }
      *(f16x8*)&sXh[xr * LDP + xs4] = hi;
      *(f16x8*)&sXl[xr * LDP + xs4] = lo;
    }
    __syncthreads();
    // ---- fragments + 3-product MFMA ----
    f16x8 bh[8], bl[8];
#pragma unroll
    for (int n = 0; n < 8; ++n) {
      int col = wn * 128 + n * 16 + l15;
      bh[n] = *(const f16x8*)&sWh[col * LDP + l4 * 8];
      bl[n] = *(const f16x8*)&sWl[col * LDP + l4 * 8];
    }
#pragma unroll
    for (int m = 0; m < 4; ++m) {
      int r = wm * 64 + m * 16 + l15;
      f16x8 ah = *(const f16x8*)&sXh[r * LDP + l4 * 8];
      f16x8 al = *(const f16x8*)&sXl[r * LDP + l4 * 8];
      f16x8 ahs;
#pragma unroll
      for (int j = 0; j < 8; ++j) ahs[j] = ah[j] * (f16)0.00390625f;  // ah * 2^-8
#pragma unroll
      for (int n = 0; n < 8; ++n) {
        acc[m][n] = __builtin_amdgcn_mfma_f32_16x16x32_f16(ah, bh[n], acc[m][n], 0, 0, 0);
        acc[m][n] = __builtin_amdgcn_mfma_f32_16x16x32_f16(ahs, bl[n], acc[m][n], 0, 0, 0);
        acc[m][n] = __builtin_amdgcn_mfma_f32_16x16x32_f16(al, bh[n], acc[m][n], 0, 0, 0);
      }
    }
  }
  __syncthreads();

  // ================= epilogue (h held at scale 2^12 in acc) =================
  // h += b1 (scaled)
#pragma unroll
  for (int m = 0; m < 4; ++m)
#pragma unroll
    for (int n = 0; n < 8; ++n) {
      int col = wn * 128 + n * 16 + l15;
      float bb = sB1[col];
#pragma unroll
      for (int r = 0; r < 4; ++r) acc[m][n][r] += bb;
    }

  // row stats: per-thread partial over its 8 cols, shfl over the 16 col-lanes,
  // deterministic cross-wave combine via LDS partials.
#pragma unroll
  for (int m = 0; m < 4; ++m) {
    float s1[4] = {0, 0, 0, 0};
    float s2[4] = {0, 0, 0, 0};
#pragma unroll
    for (int n = 0; n < 8; ++n)
#pragma unroll
      for (int r = 0; r < 4; ++r) {
        float v = acc[m][n][r];
        s1[r] += v;
        s2[r] = fmaf(v, v, s2[r]);
      }
#pragma unroll
    for (int d = 1; d < 16; d <<= 1)
#pragma unroll
      for (int r = 0; r < 4; ++r) {
        s1[r] += __shfl_xor(s1[r], d);
        s2[r] += __shfl_xor(s2[r], d);
      }
    if (l15 == 0) {
      int rb = wm * 64 + m * 16 + l4 * 4;
#pragma unroll
      for (int r = 0; r < 4; ++r) {
        sStat[wn][rb + r][0] = s1[r];
        sStat[wn][rb + r][1] = s2[r];
      }
    }
  }
  __syncthreads();
  if (tid < BM) {
    float s1 = sStat[0][tid][0] + sStat[1][tid][0] + sStat[2][tid][0] + sStat[3][tid][0];
    float s2 = sStat[0][tid][1] + sStat[1][tid][1] + sStat[2][tid][1] + sStat[3][tid][1];
    float mu = s1 * (1.0f / 512.0f);
    float var = s2 * (1.0f / 512.0f) - mu * mu;
    sMu[tid] = mu;
    // eps scaled by (2^12)^2; (h_s-mu_s)*rs == exact true normalized value
    sRs[tid] = 1.0f / sqrtf(var + (1e-5f * 4096.0f * 4096.0f));
  }
  __syncthreads();

  // LN + exact-erf GELU + logits (partial per wave, deterministic combine)
#pragma unroll
  for (int m = 0; m < 4; ++m) {
    float lg[4][8];
#pragma unroll
    for (int r = 0; r < 4; ++r)
#pragma unroll
      for (int e = 0; e < 8; ++e) lg[r][e] = 0.0f;
    int rb = wm * 64 + m * 16 + l4 * 4;
    float mu_r[4], rs_r[4];
#pragma unroll
    for (int r = 0; r < 4; ++r) {
      mu_r[r] = sMu[rb + r];
      rs_r[r] = sRs[rb + r];
    }
#pragma unroll
    for (int n = 0; n < 8; ++n) {
      int col = wn * 128 + n * 16 + l15;
      float lw = sLnw[col], lb = sLnb[col];
#pragma unroll
      for (int r = 0; r < 4; ++r) {
        float hn = (acc[m][n][r] - mu_r[r]) * rs_r[r];
        float y = fmaf(hn, lw, lb);
        float g = 0.5f * y * (1.0f + erff(y * 0.70710678118654752440f));
#pragma unroll
        for (int e = 0; e < 8; ++e) lg[r][e] = fmaf(g, sW2T[e][col], lg[r][e]);
      }
    }
#pragma unroll
    for (int d = 1; d < 16; d <<= 1)
#pragma unroll
      for (int r = 0; r < 4; ++r)
#pragma unroll
        for (int e = 0; e < 8; ++e) lg[r][e] += __shfl_xor(lg[r][e], d);
    if (l15 == 0) {
#pragma unroll
      for (int r = 0; r < 4; ++r)
#pragma unroll
        for (int e = 0; e < 8; ++e) sLog[wn][rb + r][e] = lg[r][e];
    }
  }
  __syncthreads();

  // top-2 + sparse softmax + write + load-balance partials
  if (tid < BM) {
    float v[8];
#pragma unroll
    for (int e = 0; e < 8; ++e)
      v[e] = sLog[0][tid][e] + sLog[1][tid][e] + sLog[2][tid][e] + sLog[3][tid][e] + b2[e];
    float m1 = v[0];
    int i1 = 0;
#pragma unroll
    for (int e = 1; e < 8; ++e)
      if (v[e] > m1) { m1 = v[e]; i1 = e; }   // strict > : lowest index wins ties (= top_k)
    float m2 = -3.0e38f;
    int i2 = -1;
#pragma unroll
    for (int e = 0; e < 8; ++e)
      if (e != i1 && v[e] > m2) { m2 = v[e]; i2 = e; }
    float dd = expf(m2 - m1);
    float inv = 1.0f / (1.0f + dd);
    float wA = inv, wB = dd * inv;
    float o[8];
#pragma unroll
    for (int e = 0; e < 8; ++e)
      o[e] = (e == i1) ? wA : ((e == i2) ? wB : 0.0f);
    float4 o0 = {o[0], o[1], o[2], o[3]};
    float4 o1 = {o[4], o[5], o[6], o[7]};
    float4* op = (float4*)&out[(row0 + tid) * 8];
    op[0] = o0;
    op[1] = o1;
    atomicAdd(&sF[i1], 1.0f);
    atomicAdd(&sF[i2], 1.0f);
    atomicAdd(&sP[i1], wA);
    atomicAdd(&sP[i2], wB);
  }
  __syncthreads();
  if (tid < E_DIM) {
    atomicAdd(&gacc[tid], sF[tid]);
    atomicAdd(&gacc[E_DIM + tid], sP[tid]);
  }
}

// ---------------- finalize load-balance loss --------------------------------
__global__ void lb_final(const float* __restrict__ gacc, float* __restrict__ out) {
  if (threadIdx.x == 0) {
    const float invB = 1.0f / 65536.0f;
    float s = 0.0f;
#pragma unroll
    for (int e = 0; e < 8; ++e) s += (gacc[e] * invB) * (gacc[8 + e] * invB);
    out[(size_t)B_ROWS * E_DIM] = 0.01f * 8.0f * s;
  }
}

// ---------------- launch ----------------------------------------------------
extern "C" void kernel_launch(void* const* d_in, const int* in_sizes, int n_in,
                              void* d_out, int out_size, void* d_ws, size_t ws_size,
                              hipStream_t stream) {
  (void)in_sizes; (void)n_in; (void)out_size; (void)ws_size;
  const float* x = (const float*)d_in[0];
  const float* W1 = (const float*)d_in[1];
  const float* b1 = (const float*)d_in[2];
  const float* lnw = (const float*)d_in[3];
  const float* lnb = (const float*)d_in[4];
  const float* W2 = (const float*)d_in[5];
  const float* b2 = (const float*)d_in[6];
  float* out = (float*)d_out;
  f16* wh = (f16*)d_ws;
  f16* wl = wh + IMG_TOTAL;
  float* gacc = (float*)((char*)d_ws + ACC_OFF_BYTES);  // ws needs ~2.63 MB

  zero_acc<<<1, 64, 0, stream>>>(gacc);
  prep_split<<<(D_DIM * H_DIM) / 256, 256, 0, stream>>>(W1, wh, wl);
  fused_main<<<B_ROWS / BM, THREADS, 0, stream>>>(x, wh, wl, b1, lnw, lnb, W2, b2,
                                                  out, gacc);
  lb_final<<<1, 64, 0, stream>>>(gacc, out);
}

// Round 2
// 263.661 us; speedup vs baseline: 1.1761x; 1.1761x over previous
//
#include <hip/hip_runtime.h>
#include <cstdint>
#include <cstddef>

// ---------------------------------------------------------------------------
// GatingNetwork r2: fp16x2 Markidis 3-product MFMA for x@W1 (fp32-grade
// accuracy), W1 hi/lo images read straight from L2 in fragment order (no LDS
// staging), 64-row blocks, double-buffered x tile, epilogue LDS overlaid on
// GEMM LDS, target 2 blocks/CU.
// Scales: A=64x, B=64w, lo-of-B pre-scaled 2^8; h held at scale 2^12.
// ---------------------------------------------------------------------------

typedef _Float16 f16;
typedef _Float16 f16x4 __attribute__((ext_vector_type(4)));
typedef _Float16 f16x8 __attribute__((ext_vector_type(8)));
typedef float f32x4 __attribute__((ext_vector_type(4)));

#define B_ROWS 65536
#define D_DIM 1024
#define H_DIM 512
#define E_DIM 8
#define BM 64
#define BK 32
#define NCHUNK 32
#define THREADS 512
#define LDP 40                          // x-tile row stride in halves (80 B, mult of 16)
#define IMG_CH (H_DIM * BK)             // 16384 halves per K-chunk image
#define IMG_TOTAL (NCHUNK * IMG_CH)     // 524288 halves = 1 MB per image
#define GACC_OFF ((size_t)2 * IMG_TOTAL * sizeof(f16))  // 2 MB

// ---- prep: split W1 into fp16 hi/lo images in MFMA B-fragment order --------
// img[c][col][kk] (kk = k within chunk), unpadded: lane reads col*32 + l4*8.
__global__ void prep_split(const float* __restrict__ W1,
                           f16* __restrict__ wh, f16* __restrict__ wl) {
  int id = blockIdx.x * 256 + threadIdx.x;   // 65536 threads
  int h = id & (H_DIM - 1);
  int kg = id >> 9;                          // 0..127
  int c = kg >> 2;
  int kk0 = (kg & 3) * 8;
  int k0 = kg * 8;
  f16x8 hv, lv;
#pragma unroll
  for (int j = 0; j < 8; ++j) {
    float v = W1[(size_t)(k0 + j) * H_DIM + h] * 64.0f;
    f16 hi = (f16)v;
    hv[j] = hi;
    lv[j] = (f16)((v - (float)hi) * 256.0f);  // residual pre-scaled 2^8 (normal range)
  }
  size_t o = (size_t)c * IMG_CH + (size_t)h * BK + kk0;
  *(f16x8*)&wh[o] = hv;
  *(f16x8*)&wl[o] = lv;
}

__global__ void zero_acc(float* __restrict__ acc) {
  if (threadIdx.x < 16) acc[threadIdx.x] = 0.0f;
}

// ---- main fused kernel -----------------------------------------------------
__global__ __launch_bounds__(THREADS, 4) void fused_main(
    const float* __restrict__ x,
    const f16* __restrict__ wh, const f16* __restrict__ wl,
    const float* __restrict__ b1, const float* __restrict__ lnw,
    const float* __restrict__ lnb, const float* __restrict__ W2,
    const float* __restrict__ b2, float* __restrict__ out,
    float* __restrict__ gacc) {
  // one overlaid LDS pool: GEMM phase uses [0,20480); epilogue uses [0,43584)
  __shared__ __align__(16) char pool[43584];
  f16* sX = (f16*)pool;  // [2 buf][hi(2560)|lo(2560)] halves, buf stride 5120

  const int tid = threadIdx.x;
  const int lane = tid & 63;
  const int wv = tid >> 6;        // 0..7 : wave owns cols wv*64..+63, all 64 rows
  const int l15 = lane & 15;
  const int l4 = lane >> 4;       // 0..3
  const int64_t row0 = (int64_t)blockIdx.x * BM;

  // staging coords: thread t handles row t>>3, 4 floats at col (t&7)*4
  const int srow = tid >> 3;
  const int sc4 = (tid & 7) * 4;
  const float* xp = x + (row0 + srow) * D_DIM + sc4;
  const int swo = srow * LDP + sc4;

  // B fragment base (fragment-order image: col*32 + l4*8 halves)
  const int col0 = wv * 64 + l15;
  const f16* whp = wh + (size_t)col0 * BK + l4 * 8;
  const f16* wlp = wl + (size_t)col0 * BK + l4 * 8;

  f32x4 acc[4][4];
#pragma unroll
  for (int m = 0; m < 4; ++m)
#pragma unroll
    for (int n = 0; n < 4; ++n) acc[m][n] = (f32x4){0.f, 0.f, 0.f, 0.f};

  float4 xv = *(const float4*)xp;  // chunk 0 prefetch

  for (int c = 0; c < NCHUNK; ++c) {
    const int bo = (c & 1) * 5120;
    // split & stage chunk c
    {
      float vv[4] = {xv.x, xv.y, xv.z, xv.w};
      f16x4 hv, lv;
#pragma unroll
      for (int j = 0; j < 4; ++j) {
        float v = vv[j] * 64.0f;
        f16 hh = (f16)v;
        hv[j] = hh;
        lv[j] = (f16)(v - (float)hh);
      }
      *(f16x4*)&sX[bo + swo] = hv;
      *(f16x4*)&sX[bo + 2560 + swo] = lv;
    }
    if (c + 1 < NCHUNK) xv = *(const float4*)(xp + (c + 1) * BK);  // prefetch c+1
    __syncthreads();

    const f16* whc = whp + (size_t)c * IMG_CH;
    const f16* wlc = wlp + (size_t)c * IMG_CH;
    f16x8 bfrag[4];
    // pass 1: hi-B x (ah + al)
#pragma unroll
    for (int n = 0; n < 4; ++n) bfrag[n] = *(const f16x8*)(whc + n * 512);
#pragma unroll
    for (int m = 0; m < 4; ++m) {
      const int ao = bo + (m * 16 + l15) * LDP + l4 * 8;
      f16x8 ah = *(const f16x8*)&sX[ao];
      f16x8 al = *(const f16x8*)&sX[ao + 2560];
#pragma unroll
      for (int n = 0; n < 4; ++n) {
        acc[m][n] = __builtin_amdgcn_mfma_f32_16x16x32_f16(ah, bfrag[n], acc[m][n], 0, 0, 0);
        acc[m][n] = __builtin_amdgcn_mfma_f32_16x16x32_f16(al, bfrag[n], acc[m][n], 0, 0, 0);
      }
    }
    // pass 2: lo-B x (ah * 2^-8)
#pragma unroll
    for (int n = 0; n < 4; ++n) bfrag[n] = *(const f16x8*)(wlc + n * 512);
#pragma unroll
    for (int m = 0; m < 4; ++m) {
      const int ao = bo + (m * 16 + l15) * LDP + l4 * 8;
      f16x8 ah = *(const f16x8*)&sX[ao];
      f16x8 ahs;
#pragma unroll
      for (int j = 0; j < 8; ++j) ahs[j] = ah[j] * (f16)0.00390625f;  // 2^-8
#pragma unroll
      for (int n = 0; n < 4; ++n)
        acc[m][n] = __builtin_amdgcn_mfma_f32_16x16x32_f16(ahs, bfrag[n], acc[m][n], 0, 0, 0);
    }
  }
  __syncthreads();  // GEMM done; safe to overlay epilogue region

  // ---------------- epilogue (h at scale 2^12 in acc) -----------------------
  float* eW2T = (float*)pool;                  // [8][512] transposed W2
  float* eB1 = (float*)(pool + 16384);         // pre-scaled x4096
  float* eLnw = (float*)(pool + 18432);
  float* eLnb = (float*)(pool + 20480);
  float* eStat = (float*)(pool + 22528);       // [8][64][2]
  float* eLog = (float*)(pool + 26624);        // [8][64][8]
  float* eMu = (float*)(pool + 43008);         // [64]
  float* eRs = (float*)(pool + 43264);         // [64]
  float* eFP = (float*)(pool + 43520);         // [16]

  for (int i = tid; i < H_DIM * E_DIM; i += THREADS) {
    int cc = i >> 3, e = i & 7;
    eW2T[e * H_DIM + cc] = W2[i];
  }
  eB1[tid] = b1[tid] * 4096.0f;   // THREADS == H_DIM
  eLnw[tid] = lnw[tid];
  eLnb[tid] = lnb[tid];
  if (tid < 16) eFP[tid] = 0.0f;
  __syncthreads();

  // h += b1 (scaled)
#pragma unroll
  for (int n = 0; n < 4; ++n) {
    float bb = eB1[wv * 64 + n * 16 + l15];
#pragma unroll
    for (int m = 0; m < 4; ++m)
#pragma unroll
      for (int r = 0; r < 4; ++r) acc[m][n][r] += bb;
  }

  // row stats: partial over this wave's 64 cols, then deterministic combine
#pragma unroll
  for (int m = 0; m < 4; ++m) {
    float s1[4] = {0, 0, 0, 0};
    float s2[4] = {0, 0, 0, 0};
#pragma unroll
    for (int n = 0; n < 4; ++n)
#pragma unroll
      for (int r = 0; r < 4; ++r) {
        float v = acc[m][n][r];
        s1[r] += v;
        s2[r] = fmaf(v, v, s2[r]);
      }
#pragma unroll
    for (int d = 1; d < 16; d <<= 1)
#pragma unroll
      for (int r = 0; r < 4; ++r) {
        s1[r] += __shfl_xor(s1[r], d);
        s2[r] += __shfl_xor(s2[r], d);
      }
    if (l15 == 0) {
      int rb = m * 16 + l4 * 4;
#pragma unroll
      for (int r = 0; r < 4; ++r) {
        eStat[(wv * 64 + rb + r) * 2 + 0] = s1[r];
        eStat[(wv * 64 + rb + r) * 2 + 1] = s2[r];
      }
    }
  }
  __syncthreads();
  if (tid < BM) {
    float s1 = 0.0f, s2 = 0.0f;
#pragma unroll
    for (int w = 0; w < 8; ++w) {
      s1 += eStat[(w * 64 + tid) * 2 + 0];
      s2 += eStat[(w * 64 + tid) * 2 + 1];
    }
    float mu = s1 * (1.0f / 512.0f);
    float var = s2 * (1.0f / 512.0f) - mu * mu;
    eMu[tid] = mu;
    eRs[tid] = 1.0f / sqrtf(var + (1e-5f * 4096.0f * 4096.0f));
  }
  __syncthreads();

  // LN + exact-erf GELU + per-wave partial logits
#pragma unroll
  for (int m = 0; m < 4; ++m) {
    float lg[4][8];
#pragma unroll
    for (int r = 0; r < 4; ++r)
#pragma unroll
      for (int e = 0; e < 8; ++e) lg[r][e] = 0.0f;
    int rb = m * 16 + l4 * 4;
    float mu_r[4], rs_r[4];
#pragma unroll
    for (int r = 0; r < 4; ++r) {
      mu_r[r] = eMu[rb + r];
      rs_r[r] = eRs[rb + r];
    }
#pragma unroll
    for (int n = 0; n < 4; ++n) {
      int col = wv * 64 + n * 16 + l15;
      float lw = eLnw[col], lb = eLnb[col];
#pragma unroll
      for (int r = 0; r < 4; ++r) {
        float hn = (acc[m][n][r] - mu_r[r]) * rs_r[r];
        float y = fmaf(hn, lw, lb);
        float g = 0.5f * y * (1.0f + erff(y * 0.70710678118654752440f));
#pragma unroll
        for (int e = 0; e < 8; ++e) lg[r][e] = fmaf(g, eW2T[e * H_DIM + col], lg[r][e]);
      }
    }
#pragma unroll
    for (int d = 1; d < 16; d <<= 1)
#pragma unroll
      for (int r = 0; r < 4; ++r)
#pragma unroll
        for (int e = 0; e < 8; ++e) lg[r][e] += __shfl_xor(lg[r][e], d);
    if (l15 == 0) {
#pragma unroll
      for (int r = 0; r < 4; ++r)
#pragma unroll
        for (int e = 0; e < 8; ++e) eLog[(wv * 64 + rb + r) * 8 + e] = lg[r][e];
    }
  }
  __syncthreads();

  // top-2 + sparse softmax + write + load-balance partials
  if (tid < BM) {
    float v[8];
#pragma unroll
    for (int e = 0; e < 8; ++e) {
      float s = b2[e];
#pragma unroll
      for (int w = 0; w < 8; ++w) s += eLog[(w * 64 + tid) * 8 + e];
      v[e] = s;
    }
    float m1 = v[0];
    int i1 = 0;
#pragma unroll
    for (int e = 1; e < 8; ++e)
      if (v[e] > m1) { m1 = v[e]; i1 = e; }   // strict >: lowest index wins ties
    float m2 = -3.0e38f;
    int i2 = -1;
#pragma unroll
    for (int e = 0; e < 8; ++e)
      if (e != i1 && v[e] > m2) { m2 = v[e]; i2 = e; }
    float dd = expf(m2 - m1);
    float inv = 1.0f / (1.0f + dd);
    float wA = inv, wB = dd * inv;
    float o[8];
#pragma unroll
    for (int e = 0; e < 8; ++e)
      o[e] = (e == i1) ? wA : ((e == i2) ? wB : 0.0f);
    float4* op = (float4*)&out[(row0 + tid) * 8];
    op[0] = (float4){o[0], o[1], o[2], o[3]};
    op[1] = (float4){o[4], o[5], o[6], o[7]};
    atomicAdd(&eFP[i1], 1.0f);
    atomicAdd(&eFP[i2], 1.0f);
    atomicAdd(&eFP[8 + i1], wA);
    atomicAdd(&eFP[8 + i2], wB);
  }
  __syncthreads();
  if (tid < 16) atomicAdd(&gacc[tid], eFP[tid]);
}

// ---- finalize load-balance loss --------------------------------------------
__global__ void lb_final(const float* __restrict__ gacc, float* __restrict__ out) {
  if (threadIdx.x == 0) {
    const float invB = 1.0f / 65536.0f;
    float s = 0.0f;
#pragma unroll
    for (int e = 0; e < 8; ++e) s += (gacc[e] * invB) * (gacc[8 + e] * invB);
    out[(size_t)B_ROWS * E_DIM] = 0.01f * 8.0f * s;
  }
}

// ---- launch ----------------------------------------------------------------
extern "C" void kernel_launch(void* const* d_in, const int* in_sizes, int n_in,
                              void* d_out, int out_size, void* d_ws, size_t ws_size,
                              hipStream_t stream) {
  (void)in_sizes; (void)n_in; (void)out_size; (void)ws_size;
  const float* x = (const float*)d_in[0];
  const float* W1 = (const float*)d_in[1];
  const float* b1 = (const float*)d_in[2];
  const float* lnw = (const float*)d_in[3];
  const float* lnb = (const float*)d_in[4];
  const float* W2 = (const float*)d_in[5];
  const float* b2 = (const float*)d_in[6];
  float* out = (float*)d_out;
  f16* wh = (f16*)d_ws;
  f16* wl = wh + IMG_TOTAL;
  float* gacc = (float*)((char*)d_ws + GACC_OFF);  // ws needs ~2.1 MB

  zero_acc<<<1, 64, 0, stream>>>(gacc);
  prep_split<<<(D_DIM * H_DIM / 8) / 256, 256, 0, stream>>>(W1, wh, wl);
  fused_main<<<B_ROWS / BM, THREADS, 0, stream>>>(x, wh, wl, b1, lnw, lnb, W2, b2,
                                                  out, gacc);
  lb_final<<<1, 64, 0, stream>>>(gacc, out);
}